// Round 7
// baseline (453.062 us; speedup 1.0000x reference)
//
#include <hip/hip_runtime.h>
#include <hip/hip_bf16.h>

// Problem constants: B=2048, L=64, V=4096, D=64, H=8, P=62

typedef __attribute__((ext_vector_type(8))) short short8;
typedef __attribute__((ext_vector_type(4))) float f32x4;

union FragU { uint4 u; short8 v; };

__device__ __forceinline__ unsigned short f2bf(float f) {
    union { float f; unsigned int i; } c; c.f = f;
    unsigned int i = c.i;
    unsigned int r = (i + 0x7fffu + ((i >> 16) & 1u)) >> 16;
    return (unsigned short)r;
}
__device__ __forceinline__ float asf(unsigned int u) {
    union { unsigned int i; float f; } c; c.i = u; return c.f;
}
__device__ __forceinline__ float bfsel(uint2 g, int i) {
    unsigned u = (i < 2) ? g.x : g.y;
    return asf((i & 1) ? (u & 0xffff0000u) : (u << 16));
}
// pack two f32 -> one dword of 2 bf16 (lo, hi). Manual RNE (proven r1-r4).
__device__ __forceinline__ unsigned pk2(float lo, float hi) {
    return (unsigned)f2bf(lo) | ((unsigned)f2bf(hi) << 16);
}

// XOR-swizzled LDS addressing: 64 rows x 32 dwords, bank = dw ^ 4*(row&7)
__device__ __forceinline__ int swzi(int row, int dw4) {          // dw4 4-aligned
    return (row << 5) + (dw4 ^ ((row & 7) << 2));
}
__device__ __forceinline__ int swzs(int row, int dw) {           // any dword
    return (row << 5) + (((dw & ~3) ^ ((row & 7) << 2)) | (dw & 3));
}

// xor-1 lane-pair pack: lane holds val[nt] for col 16*nt+c of row `row`.
__device__ __forceinline__ void packstore4(unsigned* S, int row, int c,
                                           float v0, float v1, float v2, float v3) {
    float p0 = __shfl_xor(v0, 1), p1 = __shfl_xor(v1, 1);
    float p2 = __shfl_xor(v2, 1), p3 = __shfl_xor(v3, 1);
    int odd = c & 1;
    float x0 = odd ? p2 : v0, y0 = odd ? v2 : p0;
    float x1 = odd ? p3 : v1, y1 = odd ? v3 : p1;
    unsigned a0 = pk2(x0, y0), a1 = pk2(x1, y1);
    int ba = (c >> 1) + (odd ? 16 : 0);
    S[swzs(row, ba)] = a0;
    S[swzs(row, ba + 8)] = a1;
}

// ---------------------------------------------------------------------------
// Kernel A (merged): blocks 0..1535 = qkv table GEMM; block 1536 = trig tables
// ---------------------------------------------------------------------------
__global__ __launch_bounds__(256) void k_pre(const float* __restrict__ W_emb,
                                             const float* __restrict__ W_qkv,
                                             const float* __restrict__ W_pos,
                                             unsigned short* __restrict__ qkvb,
                                             unsigned short* __restrict__ cst,
                                             unsigned short* __restrict__ csl,
                                             unsigned short* __restrict__ wpos) {
    __shared__ float At[4096];
    __shared__ float Bt[4096];
    int t = threadIdx.x;
    if (blockIdx.x >= 1536) {
        const float w = 6.283185307179586f / 63.0f;
        for (int e = t; e < 4096; e += 256) {
            int row = e >> 6, col = e & 63;
            {
                int j = col, x = row;
                float val = 0.0f;
                if (j < 31)       val = cosf(w * (float)(((j + 1) * x) % 63));
                else if (j >= 32 && j < 63) val = sinf(w * (float)(((j - 31) * x) % 63));
                cst[e] = f2bf(val);
            }
            {
                int j = row, x = col;
                float val = 0.0f;
                if (j < 31)       val = cosf(w * (float)(((j + 1) * x) % 63));
                else if (j >= 32 && j < 63) val = sinf(w * (float)(((j - 31) * x) % 63));
                csl[e] = f2bf(val);
            }
            {
                int j = row;
                float val = 0.0f;
                if (j < 31) val = W_pos[j * 64 + col];
                else if (j >= 32 && j < 63) val = W_pos[(j - 1) * 64 + col];
                wpos[e] = f2bf(val);
            }
        }
        return;
    }
    int bt = blockIdx.x / 24, rt = blockIdx.x - bt * 24;
    int r = t >> 2, part = t & 3;
    const float4* esrc = (const float4*)(W_emb + (size_t)((bt << 6) + r) * 64 + part * 16);
    const float4* wsrc = (const float4*)(W_qkv + (size_t)((rt << 6) + r) * 64 + part * 16);
#pragma unroll
    for (int j = 0; j < 4; ++j) {
        float4 e4 = esrc[j], w4 = wsrc[j];
        int c0 = part * 16 + j * 4;
        At[(c0 + 0) * 64 + r] = e4.x; At[(c0 + 1) * 64 + r] = e4.y;
        At[(c0 + 2) * 64 + r] = e4.z; At[(c0 + 3) * 64 + r] = e4.w;
        Bt[(c0 + 0) * 64 + r] = w4.x; Bt[(c0 + 1) * 64 + r] = w4.y;
        Bt[(c0 + 2) * 64 + r] = w4.z; Bt[(c0 + 3) * 64 + r] = w4.w;
    }
    __syncthreads();
    int l0 = (t >> 4) << 2, m0 = (t & 15) << 2;
    float acc[4][4] = {};
#pragma unroll 4
    for (int k = 0; k < 64; ++k) {
        float4 a  = *(const float4*)(At + k * 64 + l0);
        float4 bb = *(const float4*)(Bt + k * 64 + m0);
        float aa[4] = {a.x, a.y, a.z, a.w};
        float bv[4] = {bb.x, bb.y, bb.z, bb.w};
#pragma unroll
        for (int i = 0; i < 4; ++i)
#pragma unroll
            for (int j = 0; j < 4; ++j)
                acc[i][j] = fmaf(aa[i], bv[j], acc[i][j]);
    }
#pragma unroll
    for (int i = 0; i < 4; ++i) {
        unsigned* dst = (unsigned*)(qkvb + (size_t)((bt << 6) + l0 + i) * 1536 + (rt << 6) + m0);
        dst[0] = pk2(acc[i][0], acc[i][1]);
        dst[1] = pk2(acc[i][2], acc[i][3]);
    }
}

// ---------------------------------------------------------------------------
// Kernel C: fused attention. Block = 2 waves = ONE (b,h) task; wave w2 owns
// rows [32*w2, 32*w2+32). LDS 16384 B (XOR-swizzled) -> 10 blocks/CU.
//   S0: Q -> SC -> E         S1: K -> UW -> V^T -> LN-out
// E is UNNORMALIZED exp(logit); the softmax denominator s is carried per-row
// into LayerNorm where rstd = rsqrt(var_O + EPS*s^2) — algebraically exact:
// (O - mu_O)/sqrt(var_O + s^2 eps) == (x - mu_x)/sqrt(var_x + eps), O = s x.
// (Plain LN-on-O is WRONG: var_x ~ eps here; cost of that bug = absmax 0.57,
// rounds 5-6.) No max-subtraction (logits are O(1); masked cols skipped).
// Output: contiguous [b][h][l][d] bf16, coalesced dwordx4 via LDS staging.
// ---------------------------------------------------------------------------
__global__ __launch_bounds__(128, 5) void k_attn(
    const int* __restrict__ inputs,
    const unsigned short* __restrict__ qkvb,
    const unsigned short* __restrict__ cstg,
    const unsigned short* __restrict__ cslg,
    const unsigned short* __restrict__ wposg,
    const float* __restrict__ ln_g,
    const float* __restrict__ ln_b,
    unsigned short* __restrict__ out_n)
{
    __shared__ __align__(16) unsigned int smem[4096]; // 16384 B
    unsigned int* S0d = smem;
    unsigned int* S1d = smem + 2048;
    int t = threadIdx.x, w2 = t >> 6, lane = t & 63;
    int b = blockIdx.x >> 3, h = blockIdx.x & 7;
    const int* toks = inputs + b * 64;
    int r = lane & 15, q = lane >> 4, c = r;
    int tk = toks[lane];
    int mt0 = 2 * w2;

    int mk[4]; float gvv[4], bvv[4];
#pragma unroll
    for (int nt = 0; nt < 4; ++nt) {
        mk[nt] = (toks[16 * nt + c] == 0);
        gvv[nt] = ln_g[16 * nt + c];
        bvv[nt] = ln_b[16 * nt + c];
    }

    // ---- gather: wave0 -> Q into S0, wave1 -> K into S1 (lane = row) ----
    {
        const uint4* src = (const uint4*)(qkvb + (size_t)tk * 1536 + (w2 ? 512 : 0) + h * 64);
        unsigned* Sd = w2 ? S1d : S0d;
#pragma unroll
        for (int j = 0; j < 8; ++j)
            *(uint4*)(Sd + swzi(lane, 4 * j)) = src[j];
    }
    __syncthreads(); // barrier 1

    f32x4 sc[2][4], acc[2][4];
    const f32x4 zf = {0.f, 0.f, 0.f, 0.f};

    // ---- GEMM1: sim = Q K^T ----
#pragma unroll
    for (int u = 0; u < 2; ++u)
#pragma unroll
        for (int nt = 0; nt < 4; ++nt) sc[u][nt] = zf;
#pragma unroll
    for (int ks = 0; ks < 2; ++ks) {
        FragU Af[2], Bf[4];
#pragma unroll
        for (int u = 0; u < 2; ++u)
            Af[u].u = *(const uint4*)(S0d + swzi(16 * (mt0 + u) + r, 16 * ks + 4 * q));
#pragma unroll
        for (int nt = 0; nt < 4; ++nt)
            Bf[nt].u = *(const uint4*)(S1d + swzi(16 * nt + r, 16 * ks + 4 * q));
#pragma unroll
        for (int u = 0; u < 2; ++u)
#pragma unroll
            for (int nt = 0; nt < 4; ++nt)
                sc[u][nt] = __builtin_amdgcn_mfma_f32_16x16x32_bf16(Af[u].v, Bf[nt].v, sc[u][nt], 0, 0, 0);
    }
    // epilogue 1: scale+mask in regs (kept), pack bf16 SC -> S0 own rows
#pragma unroll
    for (int u = 0; u < 2; ++u) {
#pragma unroll
        for (int nt = 0; nt < 4; ++nt) {
            f32x4 vv = sc[u][nt];
#pragma unroll
            for (int i = 0; i < 4; ++i) vv[i] = mk[nt] ? 0.0f : vv[i] * 0.125f;
            sc[u][nt] = vv;
        }
#pragma unroll
        for (int i = 0; i < 4; ++i) {
            int l = 16 * (mt0 + u) + 4 * q + i;
            packstore4(S0d, l, c, sc[u][0][i], sc[u][1][i], sc[u][2][i], sc[u][3][i]);
        }
    }
    __syncthreads(); // barrier 2

    // ---- GEMM2: pos_w = SC @ Wpos^T + in-reg twist -> UW in S1 own rows ----
#pragma unroll
    for (int u = 0; u < 2; ++u)
#pragma unroll
        for (int nt = 0; nt < 4; ++nt) acc[u][nt] = zf;
#pragma unroll
    for (int ks = 0; ks < 2; ++ks) {
        FragU Af[2], Bf[4];
#pragma unroll
        for (int u = 0; u < 2; ++u)
            Af[u].u = *(const uint4*)(S0d + swzi(16 * (mt0 + u) + r, 16 * ks + 4 * q));
#pragma unroll
        for (int nt = 0; nt < 4; ++nt)
            Bf[nt].u = *(const uint4*)(wposg + (16 * nt + r) * 64 + 32 * ks + 8 * q);
#pragma unroll
        for (int u = 0; u < 2; ++u)
#pragma unroll
            for (int nt = 0; nt < 4; ++nt)
                acc[u][nt] = __builtin_amdgcn_mfma_f32_16x16x32_bf16(Af[u].v, Bf[nt].v, acc[u][nt], 0, 0, 0);
    }
#pragma unroll
    for (int u = 0; u < 2; ++u) {
        int mt = mt0 + u;
        uint2 t00 = *(const uint2*)(cslg + (c) * 64 + 16 * mt + 4 * q);
        uint2 t01 = *(const uint2*)(cslg + (32 + c) * 64 + 16 * mt + 4 * q);
        uint2 t10 = *(const uint2*)(cslg + (16 + c) * 64 + 16 * mt + 4 * q);
        uint2 t11 = *(const uint2*)(cslg + (48 + c) * 64 + 16 * mt + 4 * q);
#pragma unroll
        for (int i = 0; i < 4; ++i) {
            int l = 16 * mt + 4 * q + i;
            float cv0 = bfsel(t00, i), sv0 = bfsel(t01, i);
            float cv1 = bfsel(t10, i), sv1 = bfsel(t11, i);
            float pc0 = acc[u][0][i], ps0 = acc[u][2][i];
            float pc1 = acc[u][1][i], ps1 = acc[u][3][i];
            float u0 = pc0 * cv0 - ps0 * sv0;
            float u1 = pc1 * cv1 - ps1 * sv1;
            float u2 = pc0 * sv0 + ps0 * cv0;
            float u3 = pc1 * sv1 + ps1 * cv1;
            packstore4(S1d, l, c, u0, u1, u2, u3);
        }
    }

    // ---- GEMM3: bias = UW @ CST^T ----
#pragma unroll
    for (int u = 0; u < 2; ++u)
#pragma unroll
        for (int nt = 0; nt < 4; ++nt) acc[u][nt] = zf;
#pragma unroll
    for (int ks = 0; ks < 2; ++ks) {
        FragU Af[2], Bf[4];
#pragma unroll
        for (int u = 0; u < 2; ++u)
            Af[u].u = *(const uint4*)(S1d + swzi(16 * (mt0 + u) + r, 16 * ks + 4 * q));
#pragma unroll
        for (int nt = 0; nt < 4; ++nt)
            Bf[nt].u = *(const uint4*)(cstg + (16 * nt + r) * 64 + 32 * ks + 8 * q);
#pragma unroll
        for (int u = 0; u < 2; ++u)
#pragma unroll
            for (int nt = 0; nt < 4; ++nt)
                acc[u][nt] = __builtin_amdgcn_mfma_f32_16x16x32_bf16(Af[u].v, Bf[nt].v, acc[u][nt], 0, 0, 0);
    }

    // ---- prefetch V half-row (own d-half, 64 B per lane) ----
    uint4 V4[4];
    {
        const uint4* vsrc = (const uint4*)(qkvb + (size_t)tk * 1536 + 1024 + h * 64 + 32 * w2);
#pragma unroll
        for (int j = 0; j < 4; ++j) V4[j] = vsrc[j];
    }

    // ---- E = exp(SC + bias/62) (unnormalized), row-sum s saved for LN ----
    float rs[2][4];
#pragma unroll
    for (int u = 0; u < 2; ++u)
#pragma unroll
        for (int i = 0; i < 4; ++i) {
            int l = 16 * (mt0 + u) + 4 * q + i;
            float e0 = mk[0] ? 0.f : __expf(fmaf(acc[u][0][i], 1.0f / 62.0f, sc[u][0][i]));
            float e1 = mk[1] ? 0.f : __expf(fmaf(acc[u][1][i], 1.0f / 62.0f, sc[u][1][i]));
            float e2 = mk[2] ? 0.f : __expf(fmaf(acc[u][2][i], 1.0f / 62.0f, sc[u][2][i]));
            float e3 = mk[3] ? 0.f : __expf(fmaf(acc[u][3][i], 1.0f / 62.0f, sc[u][3][i]));
            float s = e0 + e1 + e2 + e3;
            s += __shfl_xor(s, 1);
            s += __shfl_xor(s, 2);
            s += __shfl_xor(s, 4);
            s += __shfl_xor(s, 8);
            rs[u][i] = s;
            packstore4(S0d, l, c, e0, e1, e2, e3);
        }

    // ---- V^T scatter into S1 own d-half rows ----
    {
        int odd = lane & 1;
        const unsigned* Vd = (const unsigned*)V4;
#pragma unroll
        for (int jj = 0; jj < 16; ++jj) {
            unsigned my = Vd[jj];
            unsigned pr = __shfl_xor(my, 1);
            unsigned val = odd ? ((pr >> 16) | (my & 0xffff0000u))
                               : ((my & 0xffffu) | (pr << 16));
            S1d[swzs(32 * w2 + 2 * jj + odd, lane >> 1)] = val;
        }
    }
    __syncthreads(); // barrier 3

    // ---- GEMM4: O = E @ V ----
#pragma unroll
    for (int u = 0; u < 2; ++u)
#pragma unroll
        for (int nt = 0; nt < 4; ++nt) acc[u][nt] = zf;
#pragma unroll
    for (int ks = 0; ks < 2; ++ks) {
        FragU Af[2], Bf[4];
#pragma unroll
        for (int u = 0; u < 2; ++u)
            Af[u].u = *(const uint4*)(S0d + swzi(16 * (mt0 + u) + r, 16 * ks + 4 * q));
#pragma unroll
        for (int nt = 0; nt < 4; ++nt)
            Bf[nt].u = *(const uint4*)(S1d + swzi(16 * nt + r, 16 * ks + 4 * q));
#pragma unroll
        for (int u = 0; u < 2; ++u)
#pragma unroll
            for (int nt = 0; nt < 4; ++nt)
                acc[u][nt] = __builtin_amdgcn_mfma_f32_16x16x32_bf16(Af[u].v, Bf[nt].v, acc[u][nt], 0, 0, 0);
    }
    __syncthreads(); // barrier 4: all GEMM4 S1 reads done before LN writes

    // ---- LayerNorm with eps*s^2 correction -> S1 rows ----
#pragma unroll
    for (int u = 0; u < 2; ++u)
#pragma unroll
        for (int i = 0; i < 4; ++i) {
            int l = 16 * (mt0 + u) + 4 * q + i;
            float v0 = acc[u][0][i], v1 = acc[u][1][i], v2 = acc[u][2][i], v3 = acc[u][3][i];
            float s1 = v0 + v1 + v2 + v3;
            float s2 = v0 * v0 + v1 * v1 + v2 * v2 + v3 * v3;
            s1 += __shfl_xor(s1, 1); s2 += __shfl_xor(s2, 1);
            s1 += __shfl_xor(s1, 2); s2 += __shfl_xor(s2, 2);
            s1 += __shfl_xor(s1, 4); s2 += __shfl_xor(s2, 4);
            s1 += __shfl_xor(s1, 8); s2 += __shfl_xor(s2, 8);
            float mu = s1 * (1.0f / 64.0f);
            float var = s2 * (1.0f / 64.0f) - mu * mu;
            float ss = rs[u][i];
            float rstd = rsqrtf(fmaf(ss * ss, 1e-5f, var));
            float y0 = (v0 - mu) * rstd * gvv[0] + bvv[0];
            float y1 = (v1 - mu) * rstd * gvv[1] + bvv[1];
            float y2 = (v2 - mu) * rstd * gvv[2] + bvv[2];
            float y3 = (v3 - mu) * rstd * gvv[3] + bvv[3];
            packstore4(S1d, l, c, y0, y1, y2, y3);
        }

    // ---- coalesced copy: own 32 rows of S1 -> out_n[b][h][l][d] ----
    {
        unsigned* outw = (unsigned*)out_n;
        size_t hb = ((size_t)b * 8 + h) * 64;
        int row = 32 * w2 + (lane >> 1), half = lane & 1;
        unsigned* orow = outw + (hb + row) * 32 + half * 16;
#pragma unroll
        for (int j = 0; j < 4; ++j)
            *(uint4*)(orow + 4 * j) = *(const uint4*)(S1d + swzi(row, half * 16 + 4 * j));
    }
}

// ---------------------------------------------------------------------------
// Kernel D (MFMA): per b. Stage 16-l chunks of out_n[b][h][l][d] into LDS
// transposed as XT[l][d][h] (pad 8), then C_l[d][o] = X_l[d,h] @ W1^T
// (K=8 pad 32); g[b,d,o] = sum_l w_l * relu(C_l + b1). 4 waves = quadrants.
// ---------------------------------------------------------------------------
__global__ __launch_bounds__(256) void k_mlp(const int* __restrict__ inputs,
                                             const unsigned short* __restrict__ out_n,
                                             const float* __restrict__ W1,
                                             const float* __restrict__ b1,
                                             float* __restrict__ gws) {
    __shared__ unsigned short XT[8320]; // 16 rows * 520 u16 (row pad 8)
    __shared__ float wl[64];
    int t = threadIdx.x, w = t >> 6, lane = t & 63;
    int b = blockIdx.x;
    int ot = w >> 1, dt = w & 1;
    int kq = lane >> 4, n = lane & 15;

    if (t < 64) {
        int tok = inputs[b * 64 + t];
        unsigned long long bal = __ballot(tok != 0);
        int cnt = __popcll(bal);
        if (cnt < 1) cnt = 1;
        wl[t] = (tok != 0) ? 1.0f / (float)cnt : 0.0f;
    }

    FragU Wf[2];
    float b1v[2];
#pragma unroll
    for (int om = 0; om < 2; ++om) {
        int o = 32 * ot + 16 * om + n;
        b1v[om] = b1[o];
        if (kq == 0) {
            const float4* wsrc = (const float4*)(W1 + o * 8);
            float4 wa = wsrc[0], wb = wsrc[1];
            Wf[om].u.x = pk2(wa.x, wa.y);
            Wf[om].u.y = pk2(wa.z, wa.w);
            Wf[om].u.z = pk2(wb.x, wb.y);
            Wf[om].u.w = pk2(wb.z, wb.w);
        } else {
            Wf[om].u = make_uint4(0, 0, 0, 0);
        }
    }

    f32x4 racc[2][2];
    const f32x4 zf = {0.f, 0.f, 0.f, 0.f};
#pragma unroll
    for (int dm = 0; dm < 2; ++dm)
#pragma unroll
        for (int om = 0; om < 2; ++om) racc[dm][om] = zf;

    int lh = t & 7;          // h for the load phase
    int lr = (t >> 3) & 15;  // l-within-chunk
    int half = t >> 7;       // d half

    for (int cc = 0; cc < 4; ++cc) {
        __syncthreads();
        {
            const unsigned short* src = out_n + (size_t)b * 32768 + lh * 4096
                                        + (16 * cc + lr) * 64 + half * 32;
            unsigned short* dst = XT + lr * 520 + lh;
#pragma unroll
            for (int j = 0; j < 4; ++j) {
                uint4 u = ((const uint4*)src)[j];
                int d0 = half * 32 + j * 8;
                dst[(d0 + 0) * 8] = (unsigned short)(u.x & 0xffffu);
                dst[(d0 + 1) * 8] = (unsigned short)(u.x >> 16);
                dst[(d0 + 2) * 8] = (unsigned short)(u.y & 0xffffu);
                dst[(d0 + 3) * 8] = (unsigned short)(u.y >> 16);
                dst[(d0 + 4) * 8] = (unsigned short)(u.z & 0xffffu);
                dst[(d0 + 5) * 8] = (unsigned short)(u.z >> 16);
                dst[(d0 + 6) * 8] = (unsigned short)(u.w & 0xffffu);
                dst[(d0 + 7) * 8] = (unsigned short)(u.w >> 16);
            }
        }
        __syncthreads();
#pragma unroll 4
        for (int l = 0; l < 16; ++l) {
            FragU Xf[2];
#pragma unroll
            for (int dm = 0; dm < 2; ++dm) {
                if (kq == 0)
                    Xf[dm].u = *(const uint4*)(XT + l * 520 + (32 * dt + 16 * dm + n) * 8);
                else
                    Xf[dm].u = make_uint4(0, 0, 0, 0);
            }
            float wv = wl[16 * cc + l];
#pragma unroll
            for (int dm = 0; dm < 2; ++dm)
#pragma unroll
                for (int om = 0; om < 2; ++om) {
                    f32x4 C = __builtin_amdgcn_mfma_f32_16x16x32_bf16(Xf[dm].v, Wf[om].v, zf, 0, 0, 0);
#pragma unroll
                    for (int i = 0; i < 4; ++i)
                        racc[dm][om][i] = fmaf(wv, fmaxf(C[i] + b1v[om], 0.0f), racc[dm][om][i]);
                }
        }
    }
    float* gb = gws + (size_t)b * 4096;
#pragma unroll
    for (int dm = 0; dm < 2; ++dm)
#pragma unroll
        for (int om = 0; om < 2; ++om) {
            int o = 32 * ot + 16 * om + n;
#pragma unroll
            for (int i = 0; i < 4; ++i) {
                int d = 32 * dt + 16 * dm + 4 * kq + i;
                gb[d * 64 + o] = racc[dm][om][i];
            }
        }
}

// ---------------------------------------------------------------------------
// Kernel E: per name n: gbar = mean over 4 words; out = W2 @ gbar + b2
// ---------------------------------------------------------------------------
__global__ __launch_bounds__(256) void k_final(const float* __restrict__ gws,
                                               const float* __restrict__ W2,
                                               const float* __restrict__ b2,
                                               float* __restrict__ out) {
    __shared__ float gbar[4096];
    __shared__ float w2s[32 * 68];
    __shared__ float b2s[32];
    int t = threadIdx.x;
    int n = blockIdx.x;
    for (int e = t; e < 4096; e += 256) {
        size_t base = (size_t)(4 * n) * 4096 + e;
        gbar[e] = 0.25f * (gws[base] + gws[base + 4096] + gws[base + 8192] + gws[base + 12288]);
    }
    for (int e = t; e < 2048; e += 256) {
        int p = e >> 6, o = e & 63;
        w2s[p * 68 + o] = W2[e];
    }
    if (t < 32) b2s[t] = b2[t];
    __syncthreads();
#pragma unroll
    for (int jj = 0; jj < 8; ++jj) {
        int f = jj * 256 + t;
        int d = f >> 5, p = f & 31;
        float acc = b2s[p];
        for (int o4 = 0; o4 < 16; ++o4) {
            float4 gvv = *(const float4*)(gbar + d * 64 + o4 * 4);
            float4 wv = *(const float4*)(w2s + p * 68 + o4 * 4);
            acc = fmaf(gvv.x, wv.x, acc);
            acc = fmaf(gvv.y, wv.y, acc);
            acc = fmaf(gvv.z, wv.z, acc);
            acc = fmaf(gvv.w, wv.w, acc);
        }
        out[(size_t)n * 2048 + f] = acc;
    }
}

// ---------------------------------------------------------------------------
extern "C" void kernel_launch(void* const* d_in, const int* in_sizes, int n_in,
                              void* d_out, int out_size, void* d_ws, size_t ws_size,
                              hipStream_t stream) {
    const int*   inputs = (const int*)d_in[0];
    const float* W_emb  = (const float*)d_in[1];
    const float* W_qkv  = (const float*)d_in[2];
    const float* W_pos  = (const float*)d_in[3];
    const float* ln_g   = (const float*)d_in[4];
    const float* ln_b   = (const float*)d_in[5];
    const float* W1     = (const float*)d_in[6];
    const float* b1     = (const float*)d_in[7];
    const float* W2     = (const float*)d_in[8];
    const float* b2     = (const float*)d_in[9];
    float* out = (float*)d_out;

    // ws layout (u16 units unless noted): qkvb 6291456 | cst 4096 | csl 4096 |
    // wpos 4096 | gws fp32 8388608 | out_n u16 67108864
    unsigned short* qkvb = (unsigned short*)d_ws;
    unsigned short* cst  = qkvb + 6291456;
    unsigned short* csl  = cst + 4096;
    unsigned short* wpos = csl + 4096;
    float* gws = (float*)(wpos + 4096);
    unsigned short* out_n = (unsigned short*)(gws + 8388608);

    hipLaunchKernelGGL(k_pre,   dim3(1537),  dim3(256), 0, stream,
                       W_emb, W_qkv, W_pos, qkvb, cst, csl, wpos);
    hipLaunchKernelGGL(k_attn,  dim3(16384), dim3(128), 0, stream,
                       inputs, qkvb, cst, csl, wpos, ln_g, ln_b, out_n);
    hipLaunchKernelGGL(k_mlp,   dim3(2048),  dim3(256), 0, stream, inputs, out_n, W1, b1, gws);
    hipLaunchKernelGGL(k_final, dim3(512),   dim3(256), 0, stream, gws, W2, b2, out);
}

// Round 8
// 443.762 us; speedup vs baseline: 1.0210x; 1.0210x over previous
//
#include <hip/hip_runtime.h>
#include <hip/hip_bf16.h>

// Problem constants: B=2048, L=64, V=4096, D=64, H=8, P=62

typedef __attribute__((ext_vector_type(8))) short short8;
typedef __attribute__((ext_vector_type(4))) float f32x4;

union FragU { uint4 u; short8 v; };

__device__ __forceinline__ unsigned short f2bf(float f) {
    union { float f; unsigned int i; } c; c.f = f;
    unsigned int i = c.i;
    unsigned int r = (i + 0x7fffu + ((i >> 16) & 1u)) >> 16;
    return (unsigned short)r;
}
__device__ __forceinline__ float asf(unsigned int u) {
    union { unsigned int i; float f; } c; c.i = u; return c.f;
}
__device__ __forceinline__ float bfsel(uint2 g, int i) {
    unsigned u = (i < 2) ? g.x : g.y;
    return asf((i & 1) ? (u & 0xffff0000u) : (u << 16));
}
// pack two f32 -> one dword of 2 bf16 (lo, hi). Manual RNE (proven r1-r4).
__device__ __forceinline__ unsigned pk2(float lo, float hi) {
    return (unsigned)f2bf(lo) | ((unsigned)f2bf(hi) << 16);
}

// XOR-swizzled LDS addressing: 64 rows x 32 dwords, bank = dw ^ 4*(row&7)
__device__ __forceinline__ int swzi(int row, int dw4) {          // dw4 4-aligned
    return (row << 5) + (dw4 ^ ((row & 7) << 2));
}
__device__ __forceinline__ int swzs(int row, int dw) {           // any dword
    return (row << 5) + (((dw & ~3) ^ ((row & 7) << 2)) | (dw & 3));
}

// xor-1 lane-pair pack: lane holds val[nt] for col 16*nt+c of row `row`.
__device__ __forceinline__ void packstore4(unsigned* S, int row, int c,
                                           float v0, float v1, float v2, float v3) {
    float p0 = __shfl_xor(v0, 1), p1 = __shfl_xor(v1, 1);
    float p2 = __shfl_xor(v2, 1), p3 = __shfl_xor(v3, 1);
    int odd = c & 1;
    float x0 = odd ? p2 : v0, y0 = odd ? v2 : p0;
    float x1 = odd ? p3 : v1, y1 = odd ? v3 : p1;
    unsigned a0 = pk2(x0, y0), a1 = pk2(x1, y1);
    int ba = (c >> 1) + (odd ? 16 : 0);
    S[swzs(row, ba)] = a0;
    S[swzs(row, ba + 8)] = a1;
}

// ---------------------------------------------------------------------------
// Kernel A (merged): blocks 0..1535 = qkv table GEMM; block 1536 = trig tables
// ---------------------------------------------------------------------------
__global__ __launch_bounds__(256) void k_pre(const float* __restrict__ W_emb,
                                             const float* __restrict__ W_qkv,
                                             const float* __restrict__ W_pos,
                                             unsigned short* __restrict__ qkvb,
                                             unsigned short* __restrict__ cst,
                                             unsigned short* __restrict__ csl,
                                             unsigned short* __restrict__ wpos) {
    __shared__ float At[4096];
    __shared__ float Bt[4096];
    int t = threadIdx.x;
    if (blockIdx.x >= 1536) {
        const float w = 6.283185307179586f / 63.0f;
        for (int e = t; e < 4096; e += 256) {
            int row = e >> 6, col = e & 63;
            {
                int j = col, x = row;
                float val = 0.0f;
                if (j < 31)       val = cosf(w * (float)(((j + 1) * x) % 63));
                else if (j >= 32 && j < 63) val = sinf(w * (float)(((j - 31) * x) % 63));
                cst[e] = f2bf(val);
            }
            {
                int j = row, x = col;
                float val = 0.0f;
                if (j < 31)       val = cosf(w * (float)(((j + 1) * x) % 63));
                else if (j >= 32 && j < 63) val = sinf(w * (float)(((j - 31) * x) % 63));
                csl[e] = f2bf(val);
            }
            {
                int j = row;
                float val = 0.0f;
                if (j < 31) val = W_pos[j * 64 + col];
                else if (j >= 32 && j < 63) val = W_pos[(j - 1) * 64 + col];
                wpos[e] = f2bf(val);
            }
        }
        return;
    }
    int bt = blockIdx.x / 24, rt = blockIdx.x - bt * 24;
    int r = t >> 2, part = t & 3;
    const float4* esrc = (const float4*)(W_emb + (size_t)((bt << 6) + r) * 64 + part * 16);
    const float4* wsrc = (const float4*)(W_qkv + (size_t)((rt << 6) + r) * 64 + part * 16);
#pragma unroll
    for (int j = 0; j < 4; ++j) {
        float4 e4 = esrc[j], w4 = wsrc[j];
        int c0 = part * 16 + j * 4;
        At[(c0 + 0) * 64 + r] = e4.x; At[(c0 + 1) * 64 + r] = e4.y;
        At[(c0 + 2) * 64 + r] = e4.z; At[(c0 + 3) * 64 + r] = e4.w;
        Bt[(c0 + 0) * 64 + r] = w4.x; Bt[(c0 + 1) * 64 + r] = w4.y;
        Bt[(c0 + 2) * 64 + r] = w4.z; Bt[(c0 + 3) * 64 + r] = w4.w;
    }
    __syncthreads();
    int l0 = (t >> 4) << 2, m0 = (t & 15) << 2;
    float acc[4][4] = {};
#pragma unroll 4
    for (int k = 0; k < 64; ++k) {
        float4 a  = *(const float4*)(At + k * 64 + l0);
        float4 bb = *(const float4*)(Bt + k * 64 + m0);
        float aa[4] = {a.x, a.y, a.z, a.w};
        float bv[4] = {bb.x, bb.y, bb.z, bb.w};
#pragma unroll
        for (int i = 0; i < 4; ++i)
#pragma unroll
            for (int j = 0; j < 4; ++j)
                acc[i][j] = fmaf(aa[i], bv[j], acc[i][j]);
    }
#pragma unroll
    for (int i = 0; i < 4; ++i) {
        unsigned* dst = (unsigned*)(qkvb + (size_t)((bt << 6) + l0 + i) * 1536 + (rt << 6) + m0);
        dst[0] = pk2(acc[i][0], acc[i][1]);
        dst[1] = pk2(acc[i][2], acc[i][3]);
    }
}

// ---------------------------------------------------------------------------
// Kernel C: fused attention. Block = 2 waves = ONE (b,h) task; wave w2 owns
// rows [32*w2, 32*w2+32). LDS 16384 B (XOR-swizzled) -> 10 blocks/CU.
//   S0: Q -> SC -> E         S1: K -> UW -> V^T -> LN-out
// E is UNNORMALIZED exp(logit); softmax denom s carried per-row into LN:
// rstd = rsqrt(var_O + EPS*s^2) — algebraically exact (r5/r6 bug: plain LN).
// Copy-out is PER-INSTRUCTION coalesced: lane i writes base+16*i (r7 bug:
// 64B-stride lanes -> 4x sector write amplification + RMW fetches).
// ---------------------------------------------------------------------------
__global__ __launch_bounds__(128, 5) void k_attn(
    const int* __restrict__ inputs,
    const unsigned short* __restrict__ qkvb,
    const unsigned short* __restrict__ cstg,
    const unsigned short* __restrict__ cslg,
    const unsigned short* __restrict__ wposg,
    const float* __restrict__ ln_g,
    const float* __restrict__ ln_b,
    unsigned short* __restrict__ out_n)
{
    __shared__ __align__(16) unsigned int smem[4096]; // 16384 B
    unsigned int* S0d = smem;
    unsigned int* S1d = smem + 2048;
    int t = threadIdx.x, w2 = t >> 6, lane = t & 63;
    int b = blockIdx.x >> 3, h = blockIdx.x & 7;
    const int* toks = inputs + b * 64;
    int r = lane & 15, q = lane >> 4, c = r;
    int tk = toks[lane];
    int mt0 = 2 * w2;

    int mk[4]; float gvv[4], bvv[4];
#pragma unroll
    for (int nt = 0; nt < 4; ++nt) {
        mk[nt] = (toks[16 * nt + c] == 0);
        gvv[nt] = ln_g[16 * nt + c];
        bvv[nt] = ln_b[16 * nt + c];
    }

    // ---- gather: wave0 -> Q into S0, wave1 -> K into S1 (lane = row) ----
    {
        const uint4* src = (const uint4*)(qkvb + (size_t)tk * 1536 + (w2 ? 512 : 0) + h * 64);
        unsigned* Sd = w2 ? S1d : S0d;
#pragma unroll
        for (int j = 0; j < 8; ++j)
            *(uint4*)(Sd + swzi(lane, 4 * j)) = src[j];
    }
    __syncthreads(); // barrier 1

    f32x4 sc[2][4], acc[2][4];
    const f32x4 zf = {0.f, 0.f, 0.f, 0.f};

    // ---- GEMM1: sim = Q K^T ----
#pragma unroll
    for (int u = 0; u < 2; ++u)
#pragma unroll
        for (int nt = 0; nt < 4; ++nt) sc[u][nt] = zf;
#pragma unroll
    for (int ks = 0; ks < 2; ++ks) {
        FragU Af[2], Bf[4];
#pragma unroll
        for (int u = 0; u < 2; ++u)
            Af[u].u = *(const uint4*)(S0d + swzi(16 * (mt0 + u) + r, 16 * ks + 4 * q));
#pragma unroll
        for (int nt = 0; nt < 4; ++nt)
            Bf[nt].u = *(const uint4*)(S1d + swzi(16 * nt + r, 16 * ks + 4 * q));
#pragma unroll
        for (int u = 0; u < 2; ++u)
#pragma unroll
            for (int nt = 0; nt < 4; ++nt)
                sc[u][nt] = __builtin_amdgcn_mfma_f32_16x16x32_bf16(Af[u].v, Bf[nt].v, sc[u][nt], 0, 0, 0);
    }
    // epilogue 1: scale+mask in regs (kept), pack bf16 SC -> S0 own rows
#pragma unroll
    for (int u = 0; u < 2; ++u) {
#pragma unroll
        for (int nt = 0; nt < 4; ++nt) {
            f32x4 vv = sc[u][nt];
#pragma unroll
            for (int i = 0; i < 4; ++i) vv[i] = mk[nt] ? 0.0f : vv[i] * 0.125f;
            sc[u][nt] = vv;
        }
#pragma unroll
        for (int i = 0; i < 4; ++i) {
            int l = 16 * (mt0 + u) + 4 * q + i;
            packstore4(S0d, l, c, sc[u][0][i], sc[u][1][i], sc[u][2][i], sc[u][3][i]);
        }
    }
    __syncthreads(); // barrier 2

    // ---- GEMM2: pos_w = SC @ Wpos^T + in-reg twist -> UW in S1 own rows ----
#pragma unroll
    for (int u = 0; u < 2; ++u)
#pragma unroll
        for (int nt = 0; nt < 4; ++nt) acc[u][nt] = zf;
#pragma unroll
    for (int ks = 0; ks < 2; ++ks) {
        FragU Af[2], Bf[4];
#pragma unroll
        for (int u = 0; u < 2; ++u)
            Af[u].u = *(const uint4*)(S0d + swzi(16 * (mt0 + u) + r, 16 * ks + 4 * q));
#pragma unroll
        for (int nt = 0; nt < 4; ++nt)
            Bf[nt].u = *(const uint4*)(wposg + (16 * nt + r) * 64 + 32 * ks + 8 * q);
#pragma unroll
        for (int u = 0; u < 2; ++u)
#pragma unroll
            for (int nt = 0; nt < 4; ++nt)
                acc[u][nt] = __builtin_amdgcn_mfma_f32_16x16x32_bf16(Af[u].v, Bf[nt].v, acc[u][nt], 0, 0, 0);
    }
#pragma unroll
    for (int u = 0; u < 2; ++u) {
        int mt = mt0 + u;
        uint2 t00 = *(const uint2*)(cslg + (c) * 64 + 16 * mt + 4 * q);
        uint2 t01 = *(const uint2*)(cslg + (32 + c) * 64 + 16 * mt + 4 * q);
        uint2 t10 = *(const uint2*)(cslg + (16 + c) * 64 + 16 * mt + 4 * q);
        uint2 t11 = *(const uint2*)(cslg + (48 + c) * 64 + 16 * mt + 4 * q);
#pragma unroll
        for (int i = 0; i < 4; ++i) {
            int l = 16 * mt + 4 * q + i;
            float cv0 = bfsel(t00, i), sv0 = bfsel(t01, i);
            float cv1 = bfsel(t10, i), sv1 = bfsel(t11, i);
            float pc0 = acc[u][0][i], ps0 = acc[u][2][i];
            float pc1 = acc[u][1][i], ps1 = acc[u][3][i];
            float u0 = pc0 * cv0 - ps0 * sv0;
            float u1 = pc1 * cv1 - ps1 * sv1;
            float u2 = pc0 * sv0 + ps0 * cv0;
            float u3 = pc1 * sv1 + ps1 * cv1;
            packstore4(S1d, l, c, u0, u1, u2, u3);
        }
    }

    // ---- GEMM3: bias = UW @ CST^T ----
#pragma unroll
    for (int u = 0; u < 2; ++u)
#pragma unroll
        for (int nt = 0; nt < 4; ++nt) acc[u][nt] = zf;
#pragma unroll
    for (int ks = 0; ks < 2; ++ks) {
        FragU Af[2], Bf[4];
#pragma unroll
        for (int u = 0; u < 2; ++u)
            Af[u].u = *(const uint4*)(S1d + swzi(16 * (mt0 + u) + r, 16 * ks + 4 * q));
#pragma unroll
        for (int nt = 0; nt < 4; ++nt)
            Bf[nt].u = *(const uint4*)(cstg + (16 * nt + r) * 64 + 32 * ks + 8 * q);
#pragma unroll
        for (int u = 0; u < 2; ++u)
#pragma unroll
            for (int nt = 0; nt < 4; ++nt)
                acc[u][nt] = __builtin_amdgcn_mfma_f32_16x16x32_bf16(Af[u].v, Bf[nt].v, acc[u][nt], 0, 0, 0);
    }

    // ---- prefetch V half-row (own d-half, 64 B per lane) ----
    uint4 V4[4];
    {
        const uint4* vsrc = (const uint4*)(qkvb + (size_t)tk * 1536 + 1024 + h * 64 + 32 * w2);
#pragma unroll
        for (int j = 0; j < 4; ++j) V4[j] = vsrc[j];
    }

    // ---- E = exp(SC + bias/62) (unnormalized), row-sum s saved for LN ----
    float rs[2][4];
#pragma unroll
    for (int u = 0; u < 2; ++u)
#pragma unroll
        for (int i = 0; i < 4; ++i) {
            int l = 16 * (mt0 + u) + 4 * q + i;
            float e0 = mk[0] ? 0.f : __expf(fmaf(acc[u][0][i], 1.0f / 62.0f, sc[u][0][i]));
            float e1 = mk[1] ? 0.f : __expf(fmaf(acc[u][1][i], 1.0f / 62.0f, sc[u][1][i]));
            float e2 = mk[2] ? 0.f : __expf(fmaf(acc[u][2][i], 1.0f / 62.0f, sc[u][2][i]));
            float e3 = mk[3] ? 0.f : __expf(fmaf(acc[u][3][i], 1.0f / 62.0f, sc[u][3][i]));
            float s = e0 + e1 + e2 + e3;
            s += __shfl_xor(s, 1);
            s += __shfl_xor(s, 2);
            s += __shfl_xor(s, 4);
            s += __shfl_xor(s, 8);
            rs[u][i] = s;
            packstore4(S0d, l, c, e0, e1, e2, e3);
        }

    // ---- V^T scatter into S1 own d-half rows ----
    {
        int odd = lane & 1;
        const unsigned* Vd = (const unsigned*)V4;
#pragma unroll
        for (int jj = 0; jj < 16; ++jj) {
            unsigned my = Vd[jj];
            unsigned pr = __shfl_xor(my, 1);
            unsigned val = odd ? ((pr >> 16) | (my & 0xffff0000u))
                               : ((my & 0xffffu) | (pr << 16));
            S1d[swzs(32 * w2 + 2 * jj + odd, lane >> 1)] = val;
        }
    }
    __syncthreads(); // barrier 3

    // ---- GEMM4: O = E @ V ----
#pragma unroll
    for (int u = 0; u < 2; ++u)
#pragma unroll
        for (int nt = 0; nt < 4; ++nt) acc[u][nt] = zf;
#pragma unroll
    for (int ks = 0; ks < 2; ++ks) {
        FragU Af[2], Bf[4];
#pragma unroll
        for (int u = 0; u < 2; ++u)
            Af[u].u = *(const uint4*)(S0d + swzi(16 * (mt0 + u) + r, 16 * ks + 4 * q));
#pragma unroll
        for (int nt = 0; nt < 4; ++nt)
            Bf[nt].u = *(const uint4*)(S1d + swzi(16 * nt + r, 16 * ks + 4 * q));
#pragma unroll
        for (int u = 0; u < 2; ++u)
#pragma unroll
            for (int nt = 0; nt < 4; ++nt)
                acc[u][nt] = __builtin_amdgcn_mfma_f32_16x16x32_bf16(Af[u].v, Bf[nt].v, acc[u][nt], 0, 0, 0);
    }
    __syncthreads(); // barrier 4: all GEMM4 S1 reads done before LN writes

    // ---- LayerNorm with eps*s^2 correction -> S1 rows ----
#pragma unroll
    for (int u = 0; u < 2; ++u)
#pragma unroll
        for (int i = 0; i < 4; ++i) {
            int l = 16 * (mt0 + u) + 4 * q + i;
            float v0 = acc[u][0][i], v1 = acc[u][1][i], v2 = acc[u][2][i], v3 = acc[u][3][i];
            float s1 = v0 + v1 + v2 + v3;
            float s2 = v0 * v0 + v1 * v1 + v2 * v2 + v3 * v3;
            s1 += __shfl_xor(s1, 1); s2 += __shfl_xor(s2, 1);
            s1 += __shfl_xor(s1, 2); s2 += __shfl_xor(s2, 2);
            s1 += __shfl_xor(s1, 4); s2 += __shfl_xor(s2, 4);
            s1 += __shfl_xor(s1, 8); s2 += __shfl_xor(s2, 8);
            float mu = s1 * (1.0f / 64.0f);
            float var = s2 * (1.0f / 64.0f) - mu * mu;
            float ss = rs[u][i];
            float rstd = rsqrtf(fmaf(ss * ss, 1e-5f, var));
            float y0 = (v0 - mu) * rstd * gvv[0] + bvv[0];
            float y1 = (v1 - mu) * rstd * gvv[1] + bvv[1];
            float y2 = (v2 - mu) * rstd * gvv[2] + bvv[2];
            float y3 = (v3 - mu) * rstd * gvv[3] + bvv[3];
            packstore4(S1d, l, c, y0, y1, y2, y3);
        }

    // ---- copy-out: per-instruction coalesced. Instruction j writes 1 KB
    // contiguous (lane i at +16*i). Reads hit 8 lanes/row via swizzle perm. ----
    {
        unsigned* outw = (unsigned*)out_n;
        size_t base = ((size_t)b * 8 + h) * 2048; // 64 rows * 32 dwords
#pragma unroll
        for (int j = 0; j < 4; ++j) {
            int fl = 1024 * w2 + j * 256 + lane * 4;
            int row = fl >> 5, dw4 = fl & 31;
            *(uint4*)(outw + base + fl) = *(const uint4*)(S1d + swzi(row, dw4));
        }
    }
}

// ---------------------------------------------------------------------------
// Kernel D (MFMA): per b. Stage 16-l chunks of out_n[b][h][l][d] into LDS
// transposed as XT[l][d][h] (pad 8), then C_l[d][o] = X_l[d,h] @ W1^T
// (K=8 pad 32); g[b,d,o] = sum_l w_l * relu(C_l + b1). 4 waves = quadrants.
// ---------------------------------------------------------------------------
__global__ __launch_bounds__(256) void k_mlp(const int* __restrict__ inputs,
                                             const unsigned short* __restrict__ out_n,
                                             const float* __restrict__ W1,
                                             const float* __restrict__ b1,
                                             float* __restrict__ gws) {
    __shared__ unsigned short XT[8320]; // 16 rows * 520 u16 (row pad 8)
    __shared__ float wl[64];
    int t = threadIdx.x, w = t >> 6, lane = t & 63;
    int b = blockIdx.x;
    int ot = w >> 1, dt = w & 1;
    int kq = lane >> 4, n = lane & 15;

    if (t < 64) {
        int tok = inputs[b * 64 + t];
        unsigned long long bal = __ballot(tok != 0);
        int cnt = __popcll(bal);
        if (cnt < 1) cnt = 1;
        wl[t] = (tok != 0) ? 1.0f / (float)cnt : 0.0f;
    }

    FragU Wf[2];
    float b1v[2];
#pragma unroll
    for (int om = 0; om < 2; ++om) {
        int o = 32 * ot + 16 * om + n;
        b1v[om] = b1[o];
        if (kq == 0) {
            const float4* wsrc = (const float4*)(W1 + o * 8);
            float4 wa = wsrc[0], wb = wsrc[1];
            Wf[om].u.x = pk2(wa.x, wa.y);
            Wf[om].u.y = pk2(wa.z, wa.w);
            Wf[om].u.z = pk2(wb.x, wb.y);
            Wf[om].u.w = pk2(wb.z, wb.w);
        } else {
            Wf[om].u = make_uint4(0, 0, 0, 0);
        }
    }

    f32x4 racc[2][2];
    const f32x4 zf = {0.f, 0.f, 0.f, 0.f};
#pragma unroll
    for (int dm = 0; dm < 2; ++dm)
#pragma unroll
        for (int om = 0; om < 2; ++om) racc[dm][om] = zf;

    int lh = t & 7;          // h for the load phase
    int lr = (t >> 3) & 15;  // l-within-chunk
    int half = t >> 7;       // d half

    for (int cc = 0; cc < 4; ++cc) {
        __syncthreads();
        {
            const unsigned short* src = out_n + (size_t)b * 32768 + lh * 4096
                                        + (16 * cc + lr) * 64 + half * 32;
            unsigned short* dst = XT + lr * 520 + lh;
#pragma unroll
            for (int j = 0; j < 4; ++j) {
                uint4 u = ((const uint4*)src)[j];
                int d0 = half * 32 + j * 8;
                dst[(d0 + 0) * 8] = (unsigned short)(u.x & 0xffffu);
                dst[(d0 + 1) * 8] = (unsigned short)(u.x >> 16);
                dst[(d0 + 2) * 8] = (unsigned short)(u.y & 0xffffu);
                dst[(d0 + 3) * 8] = (unsigned short)(u.y >> 16);
                dst[(d0 + 4) * 8] = (unsigned short)(u.z & 0xffffu);
                dst[(d0 + 5) * 8] = (unsigned short)(u.z >> 16);
                dst[(d0 + 6) * 8] = (unsigned short)(u.w & 0xffffu);
                dst[(d0 + 7) * 8] = (unsigned short)(u.w >> 16);
            }
        }
        __syncthreads();
#pragma unroll 4
        for (int l = 0; l < 16; ++l) {
            FragU Xf[2];
#pragma unroll
            for (int dm = 0; dm < 2; ++dm) {
                if (kq == 0)
                    Xf[dm].u = *(const uint4*)(XT + l * 520 + (32 * dt + 16 * dm + n) * 8);
                else
                    Xf[dm].u = make_uint4(0, 0, 0, 0);
            }
            float wv = wl[16 * cc + l];
#pragma unroll
            for (int dm = 0; dm < 2; ++dm)
#pragma unroll
                for (int om = 0; om < 2; ++om) {
                    f32x4 C = __builtin_amdgcn_mfma_f32_16x16x32_bf16(Xf[dm].v, Wf[om].v, zf, 0, 0, 0);
#pragma unroll
                    for (int i = 0; i < 4; ++i)
                        racc[dm][om][i] = fmaf(wv, fmaxf(C[i] + b1v[om], 0.0f), racc[dm][om][i]);
                }
        }
    }
    float* gb = gws + (size_t)b * 4096;
#pragma unroll
    for (int dm = 0; dm < 2; ++dm)
#pragma unroll
        for (int om = 0; om < 2; ++om) {
            int o = 32 * ot + 16 * om + n;
#pragma unroll
            for (int i = 0; i < 4; ++i) {
                int d = 32 * dt + 16 * dm + 4 * kq + i;
                gb[d * 64 + o] = racc[dm][om][i];
            }
        }
}

// ---------------------------------------------------------------------------
// Kernel E: per name n: gbar = mean over 4 words; out = W2 @ gbar + b2
// ---------------------------------------------------------------------------
__global__ __launch_bounds__(256) void k_final(const float* __restrict__ gws,
                                               const float* __restrict__ W2,
                                               const float* __restrict__ b2,
                                               float* __restrict__ out) {
    __shared__ float gbar[4096];
    __shared__ float w2s[32 * 68];
    __shared__ float b2s[32];
    int t = threadIdx.x;
    int n = blockIdx.x;
    for (int e = t; e < 4096; e += 256) {
        size_t base = (size_t)(4 * n) * 4096 + e;
        gbar[e] = 0.25f * (gws[base] + gws[base + 4096] + gws[base + 8192] + gws[base + 12288]);
    }
    for (int e = t; e < 2048; e += 256) {
        int p = e >> 6, o = e & 63;
        w2s[p * 68 + o] = W2[e];
    }
    if (t < 32) b2s[t] = b2[t];
    __syncthreads();
#pragma unroll
    for (int jj = 0; jj < 8; ++jj) {
        int f = jj * 256 + t;
        int d = f >> 5, p = f & 31;
        float acc = b2s[p];
        for (int o4 = 0; o4 < 16; ++o4) {
            float4 gvv = *(const float4*)(gbar + d * 64 + o4 * 4);
            float4 wv = *(const float4*)(w2s + p * 68 + o4 * 4);
            acc = fmaf(gvv.x, wv.x, acc);
            acc = fmaf(gvv.y, wv.y, acc);
            acc = fmaf(gvv.z, wv.z, acc);
            acc = fmaf(gvv.w, wv.w, acc);
        }
        out[(size_t)n * 2048 + f] = acc;
    }
}

// ---------------------------------------------------------------------------
extern "C" void kernel_launch(void* const* d_in, const int* in_sizes, int n_in,
                              void* d_out, int out_size, void* d_ws, size_t ws_size,
                              hipStream_t stream) {
    const int*   inputs = (const int*)d_in[0];
    const float* W_emb  = (const float*)d_in[1];
    const float* W_qkv  = (const float*)d_in[2];
    const float* W_pos  = (const float*)d_in[3];
    const float* ln_g   = (const float*)d_in[4];
    const float* ln_b   = (const float*)d_in[5];
    const float* W1     = (const float*)d_in[6];
    const float* b1     = (const float*)d_in[7];
    const float* W2     = (const float*)d_in[8];
    const float* b2     = (const float*)d_in[9];
    float* out = (float*)d_out;

    // ws layout (u16 units unless noted): qkvb 6291456 | cst 4096 | csl 4096 |
    // wpos 4096 | gws fp32 8388608 | out_n u16 67108864
    unsigned short* qkvb = (unsigned short*)d_ws;
    unsigned short* cst  = qkvb + 6291456;
    unsigned short* csl  = cst + 4096;
    unsigned short* wpos = csl + 4096;
    float* gws = (float*)(wpos + 4096);
    unsigned short* out_n = (unsigned short*)(gws + 8388608);

    hipLaunchKernelGGL(k_pre,   dim3(1537),  dim3(256), 0, stream,
                       W_emb, W_qkv, W_pos, qkvb, cst, csl, wpos);
    hipLaunchKernelGGL(k_attn,  dim3(16384), dim3(128), 0, stream,
                       inputs, qkvb, cst, csl, wpos, ln_g, ln_b, out_n);
    hipLaunchKernelGGL(k_mlp,   dim3(2048),  dim3(256), 0, stream, inputs, out_n, W1, b1, gws);
    hipLaunchKernelGGL(k_final, dim3(512),   dim3(256), 0, stream, gws, W2, b2, out);
}